// Round 2
// baseline (99.175 us; speedup 1.0000x reference)
//
#include <hip/hip_runtime.h>
#include <hip/hip_bf16.h>

typedef float v2f __attribute__((ext_vector_type(2)));
typedef float v4f __attribute__((ext_vector_type(4)));
typedef _Float16 h2v __attribute__((ext_vector_type(2)));

#define DD 256   // input embed dim
#define HH 64    // hidden dim
#define H2 32    // f16 h-pairs

#if __has_builtin(__builtin_amdgcn_fdot2)
#define FDOT2(a, b, c) __builtin_amdgcn_fdot2((a), (b), (c), false)
#else
#define FDOT2(a, b, c) ((c) + (float)(a).x * (float)(b).x + (float)(a).y * (float)(b).y)
#endif

static __device__ __forceinline__ h2v as_h2(unsigned x) {
    union { unsigned u; h2v h; } c; c.u = x; return c.h;
}
static __device__ __forceinline__ float fast_sigmoid(float x) {
    return __builtin_amdgcn_rcpf(1.0f + __expf(-x));
}

// ---------------------------------------------------------------------------
// prep: blocks 0..127  -> U rows = ag @ W1[:256] + b1, stored f16-pair [2048][32]
//       blocks 128..255-> V      = ab @ W1[256:],      stored f16-pair [32][2048] (h2-major)
// No LDS staging for A/W: W reads are coalesced global b32 (L1/L2 hot, 128 KB total),
// A reads are wave-uniform global b128 broadcasts (each row read by exactly one block).
// ---------------------------------------------------------------------------
__global__ __launch_bounds__(256) void prep_kernel(
    const float* __restrict__ ag, const float* __restrict__ ab,
    const float* __restrict__ W1, const float* __restrict__ b1,
    h2v* __restrict__ U, h2v* __restrict__ V)
{
    __shared__ float buf[16 * 66];   // [16 rows][64 h], dword stride 66 (bank spread)

    const int t = threadIdx.x;
    const int b = blockIdx.x;
    const bool isV = (b >= 128);
    const float* __restrict__ A = isV ? ab : ag;
    const int row0 = (b & 127) * 16;
    const float* __restrict__ W = W1 + (isV ? DD * HH : 0);

    const int h = t & 63;
    const int g = t >> 6;            // wave id -> 4 rows
    const float* __restrict__ a0 = A + (row0 + g * 4) * DD;

    float acc0 = 0.f, acc1 = 0.f, acc2 = 0.f, acc3 = 0.f;
    #pragma unroll 2
    for (int k = 0; k < DD; k += 4) {
        // W: lane h -> consecutive dwords: perfectly coalesced, L1/L2-resident
        const float w0 = W[(k + 0) * HH + h];
        const float w1 = W[(k + 1) * HH + h];
        const float w2_ = W[(k + 2) * HH + h];
        const float w3 = W[(k + 3) * HH + h];
        // A: wave-uniform b128 broadcasts
        const v4f aa0 = *(const v4f*)(a0 + k);
        const v4f aa1 = *(const v4f*)(a0 + DD + k);
        const v4f aa2 = *(const v4f*)(a0 + 2 * DD + k);
        const v4f aa3 = *(const v4f*)(a0 + 3 * DD + k);
        acc0 = fmaf(aa0.x, w0, acc0); acc0 = fmaf(aa0.y, w1, acc0);
        acc0 = fmaf(aa0.z, w2_, acc0); acc0 = fmaf(aa0.w, w3, acc0);
        acc1 = fmaf(aa1.x, w0, acc1); acc1 = fmaf(aa1.y, w1, acc1);
        acc1 = fmaf(aa1.z, w2_, acc1); acc1 = fmaf(aa1.w, w3, acc1);
        acc2 = fmaf(aa2.x, w0, acc2); acc2 = fmaf(aa2.y, w1, acc2);
        acc2 = fmaf(aa2.z, w2_, acc2); acc2 = fmaf(aa2.w, w3, acc2);
        acc3 = fmaf(aa3.x, w0, acc3); acc3 = fmaf(aa3.y, w1, acc3);
        acc3 = fmaf(aa3.z, w2_, acc3); acc3 = fmaf(aa3.w, w3, acc3);
    }

    if (!isV) {
        const float bb = b1[h];
        acc0 += bb; acc1 += bb; acc2 += bb; acc3 += bb;
    }

    // fp32 results -> LDS, then pack f16 pairs with coalesced dword stores
    buf[(g * 4 + 0) * 66 + h] = acc0;
    buf[(g * 4 + 1) * 66 + h] = acc1;
    buf[(g * 4 + 2) * 66 + h] = acc2;
    buf[(g * 4 + 3) * 66 + h] = acc3;
    __syncthreads();

    #pragma unroll
    for (int i = 0; i < 2; ++i) {
        const int flat = t + i * 256;      // 512 h2-dwords per block
        if (!isV) {
            const int r = flat >> 5, h2 = flat & 31;
            h2v p;
            p.x = (_Float16)buf[r * 66 + 2 * h2];
            p.y = (_Float16)buf[r * 66 + 2 * h2 + 1];
            U[(row0 + r) * H2 + h2] = p;              // fully contiguous store
        } else {
            const int c = flat & 15, h2 = flat >> 4;
            h2v p;
            p.x = (_Float16)buf[c * 66 + 2 * h2];
            p.y = (_Float16)buf[c * 66 + 2 * h2 + 1];
            V[h2 * 2048 + row0 + c] = p;              // 64B-contiguous segments
        }
    }
}

// ---------------------------------------------------------------------------
// pair: block = 32 rows x 256 cols. 4 waves x 8 rows (wave-uniform -> u reads
// are b128 broadcasts). Thread: 8 rows x 4 cols. Inner math on packed f16
// h-pairs: v_pk_add_f16 + v_pk_max_f16 + v_dot2_f32_f16 (fp32 accumulate)
// = 1.5 VALU instr per output*h.
// ---------------------------------------------------------------------------
__global__ __launch_bounds__(256, 2) void pair_kernel(
    const h2v* __restrict__ U, const h2v* __restrict__ V,
    const float* __restrict__ W2, const float* __restrict__ b2,
    float* __restrict__ out)
{
    __shared__ unsigned u_lds[32 * H2];     // 4 KB   [row][h2]
    __shared__ unsigned vt[H2 * 256];       // 32 KB  [h2][col]
    __shared__ h2v w2l[H2];

    const int t = threadIdx.x;
    const int R = blockIdx.y * 32;
    const int C = blockIdx.x * 256;

    // stage: U tile (1024 dwords) + V tile (8192 dwords), all b128 coalesced
    {
        const uint4* Us = (const uint4*)(U + R * H2);
        ((uint4*)u_lds)[t] = Us[t];
        const uint4* Vs = (const uint4*)V;
        uint4* Vd = (uint4*)vt;
        #pragma unroll
        for (int i = 0; i < 8; ++i) {
            const int flat = t + i * 256;    // uint4 index; 64 uint4 per LDS row
            const int row = flat >> 6, c4 = flat & 63;
            Vd[flat] = Vs[row * 512 + (C >> 2) + c4];
        }
        if (t < H2) {
            h2v p; p.x = (_Float16)W2[2 * t]; p.y = (_Float16)W2[2 * t + 1];
            w2l[t] = p;
        }
    }
    __syncthreads();

    const int lane = t & 63;
    const int wv = t >> 6;
    const int r0 = wv * 8;                   // wave-uniform rows

    float acc[8][4];
    #pragma unroll
    for (int i = 0; i < 8; ++i)
        #pragma unroll
        for (int k = 0; k < 4; ++k) acc[i][k] = 0.0f;

    const h2v zero = {(_Float16)0.0f, (_Float16)0.0f};
    const uint4* ub = (const uint4*)u_lds;   // [32][8] uint4
    const uint4* vb = (const uint4*)vt;      // [32][64] uint4

    #pragma unroll
    for (int hc = 0; hc < 8; ++hc) {         // 8 chunks of 4 h2 (8 h)
        const uint4 wq = *((const uint4*)w2l + hc);           // broadcast b128
        const h2v w0 = as_h2(wq.x), w1 = as_h2(wq.y), w2_ = as_h2(wq.z), w3 = as_h2(wq.w);

        h2v vv[4][4];
        #pragma unroll
        for (int j = 0; j < 4; ++j) {        // per-lane b128: lane -> consecutive 16B
            const uint4 q = vb[(hc * 4 + j) * 64 + lane];
            vv[j][0] = as_h2(q.x); vv[j][1] = as_h2(q.y);
            vv[j][2] = as_h2(q.z); vv[j][3] = as_h2(q.w);
        }

        #pragma unroll
        for (int i = 0; i < 8; ++i) {
            const uint4 uq = ub[(r0 + i) * 8 + hc];           // broadcast b128
            const h2v u0 = as_h2(uq.x), u1 = as_h2(uq.y), u2 = as_h2(uq.z), u3 = as_h2(uq.w);
            #pragma unroll
            for (int k = 0; k < 4; ++k) {
                h2v s0 = u0 + vv[0][k]; s0 = __builtin_elementwise_max(s0, zero);
                acc[i][k] = FDOT2(s0, w0, acc[i][k]);
                h2v s1 = u1 + vv[1][k]; s1 = __builtin_elementwise_max(s1, zero);
                acc[i][k] = FDOT2(s1, w1, acc[i][k]);
                h2v s2 = u2 + vv[2][k]; s2 = __builtin_elementwise_max(s2, zero);
                acc[i][k] = FDOT2(s2, w2_, acc[i][k]);
                h2v s3 = u3 + vv[3][k]; s3 = __builtin_elementwise_max(s3, zero);
                acc[i][k] = FDOT2(s3, w3, acc[i][k]);
            }
        }
    }

    const float b2v = *b2;
    #pragma unroll
    for (int i = 0; i < 8; ++i) {
        v4f o;
        o.x = fast_sigmoid(acc[i][0] + b2v);
        o.y = fast_sigmoid(acc[i][1] + b2v);
        o.z = fast_sigmoid(acc[i][2] + b2v);
        o.w = fast_sigmoid(acc[i][3] + b2v);
        *(v4f*)(out + (size_t)(R + r0 + i) * 2048 + C + lane * 4) = o;  // 1KB/wave/row
    }
}

extern "C" void kernel_launch(void* const* d_in, const int* in_sizes, int n_in,
                              void* d_out, int out_size, void* d_ws, size_t ws_size,
                              hipStream_t stream) {
    const float* ag = (const float*)d_in[0];   // [2048][256]
    const float* ab = (const float*)d_in[1];   // [2048][256]
    const float* W1 = (const float*)d_in[2];   // [512][64]
    const float* b1 = (const float*)d_in[3];   // [64]
    const float* W2 = (const float*)d_in[4];   // [64]
    const float* b2 = (const float*)d_in[5];   // [1]
    float* out = (float*)d_out;                // [2048][2048] fp32

    h2v* U = (h2v*)d_ws;                       // [2048][32] f16-pairs (b1 folded)
    h2v* V = U + 2048 * H2;                    // [32][2048] f16-pairs, h2-major

    prep_kernel<<<256, 256, 0, stream>>>(ag, ab, W1, b1, U, V);
    pair_kernel<<<dim3(8, 64), 256, 0, stream>>>(U, V, W2, b2, out);
}

// Round 3
// 96.006 us; speedup vs baseline: 1.0330x; 1.0330x over previous
//
#include <hip/hip_runtime.h>
#include <hip/hip_bf16.h>

typedef float v2f __attribute__((ext_vector_type(2)));
typedef float v4f __attribute__((ext_vector_type(4)));
typedef _Float16 h2v __attribute__((ext_vector_type(2)));

#define DD 256   // input embed dim
#define HH 64    // hidden dim
#define H2 32    // f16 h-pairs

#if __has_builtin(__builtin_amdgcn_fdot2)
#define FDOT2(a, b, c) __builtin_amdgcn_fdot2((a), (b), (c), false)
#else
#define FDOT2(a, b, c) ((c) + (float)(a).x * (float)(b).x + (float)(a).y * (float)(b).y)
#endif

static __device__ __forceinline__ h2v as_h2(unsigned x) {
    union { unsigned u; h2v h; } c; c.u = x; return c.h;
}
static __device__ __forceinline__ float fast_sigmoid(float x) {
    return __builtin_amdgcn_rcpf(1.0f + __expf(-x));
}

// ---------------------------------------------------------------------------
// prep: blocks 0..127  -> U rows = ag @ W1[:256] + b1, stored f16-pair [2048][32]
//       blocks 128..255-> V      = ab @ W1[256:],      stored f16-pair [32][2048] (h2-major)
// W reads: coalesced global b32, L2-hot (16 MB aggregate -> ~0.5 us of L2 BW).
// A reads: wave-uniform global b128 broadcasts, single-use -> nontemporal.
// ---------------------------------------------------------------------------
__global__ __launch_bounds__(256) void prep_kernel(
    const float* __restrict__ ag, const float* __restrict__ ab,
    const float* __restrict__ W1, const float* __restrict__ b1,
    h2v* __restrict__ U, h2v* __restrict__ V)
{
    __shared__ float buf[16 * 66];   // [16 rows][64 h], dword stride 66 (bank spread)

    const int t = threadIdx.x;
    const int b = blockIdx.x;
    const bool isV = (b >= 128);
    const float* __restrict__ A = isV ? ab : ag;
    const int row0 = (b & 127) * 16;
    const float* __restrict__ W = W1 + (isV ? DD * HH : 0);

    const int h = t & 63;
    const int g = t >> 6;            // wave id -> 4 rows
    const float* __restrict__ a0 = A + (row0 + g * 4) * DD;

    float acc0 = 0.f, acc1 = 0.f, acc2 = 0.f, acc3 = 0.f;
    #pragma unroll 4
    for (int k = 0; k < DD; k += 4) {
        // W: lane h -> consecutive dwords: perfectly coalesced, L1/L2-resident
        const float w0 = W[(k + 0) * HH + h];
        const float w1 = W[(k + 1) * HH + h];
        const float w2_ = W[(k + 2) * HH + h];
        const float w3 = W[(k + 3) * HH + h];
        // A: wave-uniform b128 broadcasts, single-use stream
        const v4f aa0 = __builtin_nontemporal_load((const v4f*)(a0 + k));
        const v4f aa1 = __builtin_nontemporal_load((const v4f*)(a0 + DD + k));
        const v4f aa2 = __builtin_nontemporal_load((const v4f*)(a0 + 2 * DD + k));
        const v4f aa3 = __builtin_nontemporal_load((const v4f*)(a0 + 3 * DD + k));
        acc0 = fmaf(aa0.x, w0, acc0); acc0 = fmaf(aa0.y, w1, acc0);
        acc0 = fmaf(aa0.z, w2_, acc0); acc0 = fmaf(aa0.w, w3, acc0);
        acc1 = fmaf(aa1.x, w0, acc1); acc1 = fmaf(aa1.y, w1, acc1);
        acc1 = fmaf(aa1.z, w2_, acc1); acc1 = fmaf(aa1.w, w3, acc1);
        acc2 = fmaf(aa2.x, w0, acc2); acc2 = fmaf(aa2.y, w1, acc2);
        acc2 = fmaf(aa2.z, w2_, acc2); acc2 = fmaf(aa2.w, w3, acc2);
        acc3 = fmaf(aa3.x, w0, acc3); acc3 = fmaf(aa3.y, w1, acc3);
        acc3 = fmaf(aa3.z, w2_, acc3); acc3 = fmaf(aa3.w, w3, acc3);
    }

    if (!isV) {
        const float bb = b1[h];
        acc0 += bb; acc1 += bb; acc2 += bb; acc3 += bb;
    }

    // fp32 results -> LDS, then pack f16 pairs with coalesced dword stores
    buf[(g * 4 + 0) * 66 + h] = acc0;
    buf[(g * 4 + 1) * 66 + h] = acc1;
    buf[(g * 4 + 2) * 66 + h] = acc2;
    buf[(g * 4 + 3) * 66 + h] = acc3;
    __syncthreads();

    #pragma unroll
    for (int i = 0; i < 2; ++i) {
        const int flat = t + i * 256;      // 512 h2-dwords per block
        if (!isV) {
            const int r = flat >> 5, h2 = flat & 31;
            h2v p;
            p.x = (_Float16)buf[r * 66 + 2 * h2];
            p.y = (_Float16)buf[r * 66 + 2 * h2 + 1];
            U[(row0 + r) * H2 + h2] = p;              // fully contiguous store
        } else {
            const int c = flat & 15, h2 = flat >> 4;
            h2v p;
            p.x = (_Float16)buf[c * 66 + 2 * h2];
            p.y = (_Float16)buf[c * 66 + 2 * h2 + 1];
            V[h2 * 2048 + row0 + c] = p;              // 64B-contiguous segments
        }
    }
}

// ---------------------------------------------------------------------------
// pair: block = 32 rows x 256 cols. 4 waves x 8 rows (wave-uniform -> u reads
// are b128 broadcasts). Thread: 8 rows x 4 cols. Inner math on packed f16
// h-pairs: v_pk_add_f16 + v_pk_max_f16 + v_dot2_f32_f16 (fp32 accumulate)
// = 1.5 VALU instr per output*h  (VALU floor for the device: ~5.1 us).
// ---------------------------------------------------------------------------
__global__ __launch_bounds__(256, 2) void pair_kernel(
    const h2v* __restrict__ U, const h2v* __restrict__ V,
    const float* __restrict__ W2, const float* __restrict__ b2,
    float* __restrict__ out)
{
    __shared__ unsigned u_lds[32 * H2];     // 4 KB   [row][h2]
    __shared__ unsigned vt[H2 * 256];       // 32 KB  [h2][col]
    __shared__ h2v w2l[H2];

    const int t = threadIdx.x;
    const int R = blockIdx.y * 32;
    const int C = blockIdx.x * 256;

    // stage: U tile (1024 dwords) + V tile (8192 dwords), all b128 coalesced
    {
        const uint4* Us = (const uint4*)(U + R * H2);
        ((uint4*)u_lds)[t] = Us[t];
        const uint4* Vs = (const uint4*)V;
        uint4* Vd = (uint4*)vt;
        #pragma unroll
        for (int i = 0; i < 8; ++i) {
            const int flat = t + i * 256;    // uint4 index; 64 uint4 per LDS row
            const int row = flat >> 6, c4 = flat & 63;
            Vd[flat] = Vs[row * 512 + (C >> 2) + c4];
        }
        if (t < H2) {
            h2v p; p.x = (_Float16)W2[2 * t]; p.y = (_Float16)W2[2 * t + 1];
            w2l[t] = p;
        }
    }
    __syncthreads();

    const int lane = t & 63;
    const int wv = t >> 6;
    const int r0 = wv * 8;                   // wave-uniform rows

    float acc[8][4];
    #pragma unroll
    for (int i = 0; i < 8; ++i)
        #pragma unroll
        for (int k = 0; k < 4; ++k) acc[i][k] = 0.0f;

    const h2v zero = {(_Float16)0.0f, (_Float16)0.0f};
    const uint4* ub = (const uint4*)u_lds;   // [32][8] uint4
    const uint4* vb = (const uint4*)vt;      // [32][64] uint4

    #pragma unroll
    for (int hc = 0; hc < 8; ++hc) {         // 8 chunks of 4 h2 (8 h)
        const uint4 wq = *((const uint4*)w2l + hc);           // broadcast b128
        const h2v w0 = as_h2(wq.x), w1 = as_h2(wq.y), w2_ = as_h2(wq.z), w3 = as_h2(wq.w);

        h2v vv[4][4];
        #pragma unroll
        for (int j = 0; j < 4; ++j) {        // per-lane b128: lane -> consecutive 16B
            const uint4 q = vb[(hc * 4 + j) * 64 + lane];
            vv[j][0] = as_h2(q.x); vv[j][1] = as_h2(q.y);
            vv[j][2] = as_h2(q.z); vv[j][3] = as_h2(q.w);
        }

        #pragma unroll
        for (int i = 0; i < 8; ++i) {
            const uint4 uq = ub[(r0 + i) * 8 + hc];           // broadcast b128
            const h2v u0 = as_h2(uq.x), u1 = as_h2(uq.y), u2 = as_h2(uq.z), u3 = as_h2(uq.w);
            #pragma unroll
            for (int k = 0; k < 4; ++k) {
                h2v s0 = u0 + vv[0][k]; s0 = __builtin_elementwise_max(s0, zero);
                acc[i][k] = FDOT2(s0, w0, acc[i][k]);
                h2v s1 = u1 + vv[1][k]; s1 = __builtin_elementwise_max(s1, zero);
                acc[i][k] = FDOT2(s1, w1, acc[i][k]);
                h2v s2 = u2 + vv[2][k]; s2 = __builtin_elementwise_max(s2, zero);
                acc[i][k] = FDOT2(s2, w2_, acc[i][k]);
                h2v s3 = u3 + vv[3][k]; s3 = __builtin_elementwise_max(s3, zero);
                acc[i][k] = FDOT2(s3, w3, acc[i][k]);
            }
        }
    }

    const float b2v = *b2;
    #pragma unroll
    for (int i = 0; i < 8; ++i) {
        v4f o;
        o.x = fast_sigmoid(acc[i][0] + b2v);
        o.y = fast_sigmoid(acc[i][1] + b2v);
        o.z = fast_sigmoid(acc[i][2] + b2v);
        o.w = fast_sigmoid(acc[i][3] + b2v);
        // write-once 16.8 MB stream: nontemporal to avoid L2/L3 churn
        __builtin_nontemporal_store(o, (v4f*)(out + (size_t)(R + r0 + i) * 2048 + C + lane * 4));
    }
}

extern "C" void kernel_launch(void* const* d_in, const int* in_sizes, int n_in,
                              void* d_out, int out_size, void* d_ws, size_t ws_size,
                              hipStream_t stream) {
    const float* ag = (const float*)d_in[0];   // [2048][256]
    const float* ab = (const float*)d_in[1];   // [2048][256]
    const float* W1 = (const float*)d_in[2];   // [512][64]
    const float* b1 = (const float*)d_in[3];   // [64]
    const float* W2 = (const float*)d_in[4];   // [64]
    const float* b2 = (const float*)d_in[5];   // [1]
    float* out = (float*)d_out;                // [2048][2048] fp32

    h2v* U = (h2v*)d_ws;                       // [2048][32] f16-pairs (b1 folded)
    h2v* V = U + 2048 * H2;                    // [32][2048] f16-pairs, h2-major

    prep_kernel<<<256, 256, 0, stream>>>(ag, ab, W1, b1, U, V);
    pair_kernel<<<dim3(8, 64), 256, 0, stream>>>(U, V, W2, b2, out);
}